// Round 4
// baseline (88.629 us; speedup 1.0000x reference)
//
#include <hip/hip_runtime.h>

// AdaptiveConv: out[b,c,h,w] = sum_{idx<25} x[b,c,h+idx/5, w+idx%5] * kernel[b,idx,h,w]
// Shapes (fixed by setup_inputs): x (8,64,260,260) f32, kernel (8,25,256,256) f32,
// out (8,64,256,256) f32.

constexpr int K  = 5;
constexpr int B  = 8;
constexpr int C  = 64;
constexpr int H  = 256;
constexpr int W  = 256;
constexpr int HX = H + K - 1;   // 260
constexpr int WX = W + K - 1;   // 260
constexpr int ROWS = 4;         // output rows per thread (vertical x reuse: 8 rows -> 4 outputs)

// block = 256 threads = one full output row span (W == 256).
// grid  = (H/ROWS, B). Each thread: fixed (b, w, h0..h0+3), loops all 64 channels
// with its 4x25 kernel values held in registers (kernel read exactly once).
__global__ __launch_bounds__(256, 2)
void adaptive_conv_kernel(const float* __restrict__ x,
                          const float* __restrict__ kern,
                          float* __restrict__ out) {
    const int w  = threadIdx.x;          // 0..255, coalesced axis
    const int h0 = blockIdx.x * ROWS;    // 0..252
    const int b  = blockIdx.y;           // 0..7

    // ---- load kernel taps for my 4 output pixels into registers (once) ----
    // kern[b][idx][h0+r][w]; nontemporal: read exactly once, don't pollute L3.
    float kk[ROWS][K * K];
    {
        const float* kb = kern + (size_t)b * (K * K * H * W) + (size_t)h0 * W + w;
        #pragma unroll
        for (int idx = 0; idx < K * K; ++idx) {
            #pragma unroll
            for (int r = 0; r < ROWS; ++r) {
                kk[r][idx] = __builtin_nontemporal_load(kb + (size_t)idx * (H * W) + r * W);
            }
        }
    }

    const float* xb = x   + (size_t)b * (C * HX * WX) + (size_t)h0 * WX + w;
    float*       ob = out + (size_t)b * (C * H * W)   + (size_t)h0 * W  + w;

    for (int c = 0; c < C; ++c) {
        const float* xc = xb + (size_t)c * (HX * WX);

        // x window: rows h0..h0+7, cols w..w+4 (40 scalar loads, coalesced across
        // the wave; the 5 j-offsets alias the same cache lines -> L1 hits).
        float xv[ROWS + K - 1][K];
        #pragma unroll
        for (int r = 0; r < ROWS + K - 1; ++r) {
            #pragma unroll
            for (int j = 0; j < K; ++j) {
                xv[r][j] = xc[r * WX + j];
            }
        }

        float* oc = ob + (size_t)c * (H * W);
        #pragma unroll
        for (int r = 0; r < ROWS; ++r) {
            float acc = 0.0f;
            #pragma unroll
            for (int i = 0; i < K; ++i) {
                #pragma unroll
                for (int j = 0; j < K; ++j) {
                    acc = fmaf(xv[r + i][j], kk[r][i * K + j], acc);
                }
            }
            // out written once, never read: nontemporal store keeps L3 for x.
            __builtin_nontemporal_store(acc, oc + r * W);
        }
    }
}

extern "C" void kernel_launch(void* const* d_in, const int* in_sizes, int n_in,
                              void* d_out, int out_size, void* d_ws, size_t ws_size,
                              hipStream_t stream) {
    const float* x    = (const float*)d_in[0];
    const float* kern = (const float*)d_in[1];
    float*       out  = (float*)d_out;

    dim3 grid(H / ROWS, B);   // 64 x 8 = 512 blocks
    dim3 block(W);            // 256 threads, one per output column
    adaptive_conv_kernel<<<grid, block, 0, stream>>>(x, kern, out);
}